// Round 4
// baseline (1306.118 us; speedup 1.0000x reference)
//
#include <hip/hip_runtime.h>
#include <cfloat>

typedef _Float16 half8  __attribute__((ext_vector_type(8)));
typedef _Float16 half4v __attribute__((ext_vector_type(4)));
typedef float floatx4 __attribute__((ext_vector_type(4)));

#define NBATCH 16
#define NSEQ   2048
#define ND     512
#define NC     8192
#define NTOK   (NBATCH * NSEQ)   // 32768
#define CB     32                // codes resident per block
#define NCB    (NC / CB)         // 256 code-blocks

#define XSCALE 8.0f
#define ESCALE 64.0f
// acc = sum( (8x)*(64e) ) = 512*xy ; score = e2 - 2*xy = e2 - acc/256
#define SCORE_SCALE (2.0f / (XSCALE * ESCALE)) // 1/256

typedef const void __attribute__((address_space(1)))* gp_t;
typedef void       __attribute__((address_space(3)))* lp_t;
__device__ __forceinline__ void cp16(lp_t l, gp_t g) {
  // async global->LDS DMA, 16B per lane, LDS dst = wave-uniform base + lane*16
  __builtin_amdgcn_global_load_lds(g, l, 16, 0, 0);
}

// ---------------- prep: split-convert embed (scaled by 64) to f16 h/l ----------------
__global__ __launch_bounds__(256) void prep_embed(const float* __restrict__ embed,
                                                  _Float16* __restrict__ eh,
                                                  _Float16* __restrict__ el) {
  int idx = blockIdx.x * 256 + threadIdx.x;
  int stride = gridDim.x * 256;
  for (int i = idx; i < NC * ND; i += stride) {
    float v = ESCALE * embed[i];
    _Float16 h = (_Float16)v;
    eh[i] = h;
    el[i] = (_Float16)(v - (float)h);
  }
}

// ---------------- prep: split-convert x (scaled by 8) to f16 h/l ----------------
__global__ __launch_bounds__(256) void prep_x(const float* __restrict__ x,
                                              _Float16* __restrict__ xh,
                                              _Float16* __restrict__ xl) {
  int idx = blockIdx.x * 256 + threadIdx.x;
  int stride = gridDim.x * 256;
  const int n4 = NTOK * ND / 4;
  for (int i = idx; i < n4; i += stride) {
    float4 v = ((const float4*)x)[i];
    float vs[4] = {v.x, v.y, v.z, v.w};
    half4v h, l;
#pragma unroll
    for (int q = 0; q < 4; ++q) {
      float vv = XSCALE * vs[q];
      _Float16 hh = (_Float16)vv;
      h[q] = hh;
      l[q] = (_Float16)(vv - (float)hh);
    }
    ((half4v*)xh)[i] = h;
    ((half4v*)xl)[i] = l;
  }
}

// ---------------- prep: e2[c] = sum_d embed[c][d]^2 (fp32, unscaled) ----------------
__global__ __launch_bounds__(256) void prep_e2(const float* __restrict__ embed,
                                               float* __restrict__ e2) {
  int wave = threadIdx.x >> 6, lane = threadIdx.x & 63;
  int c = blockIdx.x * 4 + wave;
  const float* row = embed + (size_t)c * ND;
  float s = 0.f;
  for (int k = lane; k < ND; k += 64) { float v = row[k]; s = fmaf(v, v, s); }
  for (int off = 32; off > 0; off >>= 1) s += __shfl_down(s, off, 64);
  if (lane == 0) e2[c] = s;
}

// ---------------- init: per-token (score,idx) key = +inf ----------------
__global__ __launch_bounds__(256) void init_keys(unsigned long long* __restrict__ k) {
  k[blockIdx.x * 256 + threadIdx.x] = ~0ULL;
}

// ---------------- barrier-free fused GEMM + argmin ----------------
// Block: 4 waves, 32 codes (full K=512, f16 h+l) resident in 64 KB LDS,
// staged ONCE via DMA. Main loop has ZERO __syncthreads: each wave streams
// its 64-token passes, loading X fragments global->register, reading E
// fragments from LDS, 24 MFMA per kt, then folds per-token argmin and
// publishes via atomicMin on a sortable (score,idx) u64 key.
// LDS layout: [kt16][code32][granule4][8 halves], granule (code,cl) holds
// source granule cl ^ ((code>>1)&3) -> conflict-free ds_read_b128 AND
// compatible with the DMA's lane-ordered LDS writes.
__global__ __launch_bounds__(256, 2) void vq_argmin(
    const _Float16* __restrict__ xh, const _Float16* __restrict__ xl,
    const int* __restrict__ len,
    const _Float16* __restrict__ eh, const _Float16* __restrict__ el,
    const float* __restrict__ e2g,
    unsigned long long* __restrict__ pKey) {
  __shared__ _Float16 sEh[CB * ND];   // 32 KiB
  __shared__ _Float16 sEl[CB * ND];   // 32 KiB

  const int cb = blockIdx.x, b = blockIdx.y;
  const int code0 = cb * CB;
  const int L = len[b];
  const int tid = threadIdx.x, wave = tid >> 6, lane = tid & 63;
  const int quad = lane >> 4, lid = lane & 15;

  // ---- stage E chunk once (32 codes x 512 K, h+l) ----
#pragma unroll
  for (int r = 0; r < 8; ++r) {
    const int R = r * 4 + wave;                 // 0..31 rounds of 1 KiB/wave
    const int kt = R >> 1;
    const int code = (R & 1) * 16 + (lane >> 2);
    const int cl = lane & 3;
    const int csrc = cl ^ ((code >> 1) & 3);
    const size_t src = (size_t)(code0 + code) * ND + kt * 32 + csrc * 8;
    cp16((lp_t)&sEh[R * 512], (gp_t)(eh + src));
    cp16((lp_t)&sEl[R * 512], (gp_t)(el + src));
  }

  float e2v[2]; int cjv[2];
#pragma unroll
  for (int j = 0; j < 2; ++j) {
    cjv[j] = code0 + j * 16 + lid;              // C/D layout: col = lane&15
    e2v[j] = e2g[cjv[j]];
  }
  const int cswz = quad ^ ((lid >> 1) & 3);
  int boff[2];
#pragma unroll
  for (int j = 0; j < 2; ++j) boff[j] = ((j * 16 + lid) * 4 + cswz) * 8;

  __syncthreads();   // the ONLY block barrier: staging DMA drained, E visible

  for (int p = wave; p < 32; p += 4) {          // 64-token passes, wave-private
    const int s0 = p * 64;
    if (s0 >= L) continue;                      // wave-uniform skip (masked)
    const size_t tokbase = (size_t)b * NSEQ + s0;
    const _Float16* pah = xh + (tokbase + lid) * ND + quad * 8;
    const _Float16* pal = xl + (tokbase + lid) * ND + quad * 8;

    floatx4 acc[4][2];
#pragma unroll
    for (int i = 0; i < 4; ++i)
#pragma unroll
      for (int j = 0; j < 2; ++j) acc[i][j] = (floatx4){0.f, 0.f, 0.f, 0.f};

#pragma unroll 4
    for (int kt = 0; kt < 16; ++kt) {
      half8 ah[4], al[4];
#pragma unroll
      for (int i = 0; i < 4; ++i) {             // A frags: global->reg, 16B/lane
        ah[i] = *(const half8*)(pah + (size_t)i * (16 * ND) + kt * 32);
        al[i] = *(const half8*)(pal + (size_t)i * (16 * ND) + kt * 32);
      }
      half8 bh[2], bl[2];
#pragma unroll
      for (int j = 0; j < 2; ++j) {             // B frags: LDS, conflict-free
        bh[j] = *(const half8*)&sEh[kt * (CB * 32) + boff[j]];
        bl[j] = *(const half8*)&sEl[kt * (CB * 32) + boff[j]];
      }
#pragma unroll
      for (int i = 0; i < 4; ++i)
#pragma unroll
        for (int j = 0; j < 2; ++j) {
          acc[i][j] = __builtin_amdgcn_mfma_f32_16x16x32_f16(ah[i], bh[j], acc[i][j], 0, 0, 0);
          acc[i][j] = __builtin_amdgcn_mfma_f32_16x16x32_f16(ah[i], bl[j], acc[i][j], 0, 0, 0);
          acc[i][j] = __builtin_amdgcn_mfma_f32_16x16x32_f16(al[i], bh[j], acc[i][j], 0, 0, 0);
        }
    }

    // ---- per-pass argmin fold + global publish (no barriers) ----
#pragma unroll
    for (int i = 0; i < 4; ++i) {
#pragma unroll
      for (int reg = 0; reg < 4; ++reg) {
        float best = fmaf(-SCORE_SCALE, acc[i][0][reg], e2v[0]);
        int bidx = cjv[0];
        float v1 = fmaf(-SCORE_SCALE, acc[i][1][reg], e2v[1]);
        if (v1 < best) { best = v1; bidx = cjv[1]; }     // strict <: lower idx wins ties
#pragma unroll
        for (int m = 1; m < 16; m <<= 1) {               // reduce 16 cols in-quad
          float ov = __shfl_xor(best, m, 64);
          int   oi = __shfl_xor(bidx, m, 64);
          if (ov < best || (ov == best && oi < bidx)) { best = ov; bidx = oi; }
        }
        if (lid == 0) {
          int t = (int)tokbase + i * 16 + quad * 4 + reg;  // C/D row = quad*4+reg
          if (best == 0.0f) best = 0.0f;                   // normalize -0 for keying
          unsigned u = __float_as_uint(best);
          u ^= (u >> 31) ? 0xFFFFFFFFu : 0x80000000u;      // sortable fp32
          unsigned long long key = ((unsigned long long)u << 32) | (unsigned)bidx;
          atomicMin(&pKey[t], key);                        // lexicographic (score, idx)
        }
      }
    }
  }
}

// ---------------- decode key, gather code row, apply mask ----------------
__global__ __launch_bounds__(256) void vq_output(
    const float* __restrict__ embed, const int* __restrict__ len,
    const unsigned long long* __restrict__ pKey,
    float* __restrict__ out) {
  int wave = threadIdx.x >> 6, lane = threadIdx.x & 63;
  int t = blockIdx.x * 4 + wave;
  int b = t >> 11, s = t & (NSEQ - 1);
  float* outq = out + (size_t)t * ND;
  float* outind = out + (size_t)NTOK * ND;
  if (s >= len[b]) {
    float4 z = {0.f, 0.f, 0.f, 0.f};
    *(float4*)&outq[lane * 8]     = z;
    *(float4*)&outq[lane * 8 + 4] = z;
    if (lane == 0) outind[t] = -1.0f;
    return;
  }
  unsigned long long key = pKey[t];              // same addr across wave -> broadcast
  int bi = (int)(unsigned)(key & 0xFFFFFFFFULL);
  const float* er = embed + (size_t)bi * ND;
  *(float4*)&outq[lane * 8]     = *(const float4*)&er[lane * 8];
  *(float4*)&outq[lane * 8 + 4] = *(const float4*)&er[lane * 8 + 4];
  if (lane == 0) outind[t] = (float)bi;
}

extern "C" void kernel_launch(void* const* d_in, const int* in_sizes, int n_in,
                              void* d_out, int out_size, void* d_ws, size_t ws_size,
                              hipStream_t stream) {
  const float* x     = (const float*)d_in[0];
  const int*   lenp  = (const int*)d_in[1];
  const float* embed = (const float*)d_in[2];
  float* out = (float*)d_out;

  // ws: eh 8MB | el 8MB | e2 32KB | pKey 256KB | xh 32MB | xl 32MB  = 84.2 MB
  char* w = (char*)d_ws;
  size_t off = 0;
  _Float16* eh = (_Float16*)(w + off); off += (size_t)NC * ND * 2;
  _Float16* el = (_Float16*)(w + off); off += (size_t)NC * ND * 2;
  float*    e2 = (float*)(w + off);    off += (size_t)NC * 4;
  unsigned long long* pKey = (unsigned long long*)(w + off); off += (size_t)NTOK * 8;
  _Float16* xh = (_Float16*)(w + off); off += (size_t)NTOK * ND * 2;
  _Float16* xl = (_Float16*)(w + off); off += (size_t)NTOK * ND * 2;

  prep_embed<<<2048, 256, 0, stream>>>(embed, eh, el);
  prep_e2<<<NC / 4, 256, 0, stream>>>(embed, e2);
  prep_x<<<4096, 256, 0, stream>>>(x, xh, xl);
  init_keys<<<NTOK / 256, 256, 0, stream>>>(pKey);
  dim3 grid(NCB, NBATCH);   // x-fastest: co-resident blocks share batch b -> A L2 reuse
  vq_argmin<<<grid, 256, 0, stream>>>(xh, xl, lenp, eh, el, e2, pKey);
  vq_output<<<NTOK / 4, 256, 0, stream>>>(embed, lenp, pKey, out);
}

// Round 5
// 598.907 us; speedup vs baseline: 2.1808x; 2.1808x over previous
//
#include <hip/hip_runtime.h>
#include <cfloat>

typedef _Float16 half8  __attribute__((ext_vector_type(8)));
typedef _Float16 half4v __attribute__((ext_vector_type(4)));
typedef short    bf16x8 __attribute__((ext_vector_type(8)));
typedef short    bf16x4 __attribute__((ext_vector_type(4)));
typedef float    floatx4 __attribute__((ext_vector_type(4)));

#define NBATCH 16
#define NSEQ   2048
#define ND     512
#define NC     8192
#define NTOK   (NBATCH * NSEQ)   // 32768
#define NTT    (NTOK / 128)      // 256 token tiles
#define NCT    (NC / 128)        // 64 code tiles
#define KSTEPS (ND / 32)         // 16
#define MARGIN 1.0f              // bf16 worst-case score err ~0.2; 5x safety

#define XSCALE 8.0f
#define ESCALE 64.0f
// exact rescore: acc = sum((8x)*(64e)) = 512*xy ; score = e2 - acc/256
#define SCORE_SCALE (2.0f / (XSCALE * ESCALE)) // 1/256

typedef const void __attribute__((address_space(1)))* gp_t;
typedef void       __attribute__((address_space(3)))* lp_t;
__device__ __forceinline__ void cp16(lp_t l, gp_t g) {
  // async global->LDS DMA, 16B/lane, LDS dst = wave-uniform base + lane*16
  __builtin_amdgcn_global_load_lds(g, l, 16, 0, 0);
}

__device__ __forceinline__ short f2bf(float v) {   // RNE fp32->bf16
  unsigned u = __float_as_uint(v);
  return (short)((u + 0x7FFFu + ((u >> 16) & 1u)) >> 16);
}

// ---------------- prep: embed -> bf16 eb + scaled f16 split eh/el ----------------
__global__ __launch_bounds__(256) void prep_embed(const float* __restrict__ embed,
                                                  short* __restrict__ eb,
                                                  _Float16* __restrict__ eh,
                                                  _Float16* __restrict__ el) {
  int idx = blockIdx.x * 256 + threadIdx.x;
  int stride = gridDim.x * 256;
  for (int i = idx; i < NC * ND / 4; i += stride) {
    float4 v = ((const float4*)embed)[i];
    float vs[4] = {v.x, v.y, v.z, v.w};
    bf16x4 bv; half4v h, l;
#pragma unroll
    for (int q = 0; q < 4; ++q) {
      bv[q] = f2bf(vs[q]);
      float sv = ESCALE * vs[q];
      _Float16 hh = (_Float16)sv;
      h[q] = hh;
      l[q] = (_Float16)(sv - (float)hh);
    }
    ((bf16x4*)eb)[i] = bv;
    ((half4v*)eh)[i] = h;
    ((half4v*)el)[i] = l;
  }
}

// ---------------- prep: x -> bf16 xb ----------------
__global__ __launch_bounds__(256) void prep_xb(const float* __restrict__ x,
                                               short* __restrict__ xb) {
  int idx = blockIdx.x * 256 + threadIdx.x;
  int stride = gridDim.x * 256;
  for (int i = idx; i < NTOK * ND / 8; i += stride) {
    float4 a = ((const float4*)x)[2 * i];
    float4 b = ((const float4*)x)[2 * i + 1];
    float vs[8] = {a.x, a.y, a.z, a.w, b.x, b.y, b.z, b.w};
    bf16x8 o;
#pragma unroll
    for (int q = 0; q < 8; ++q) o[q] = f2bf(vs[q]);
    ((bf16x8*)xb)[i] = o;
  }
}

// ---------------- prep: e2[c] = sum_d embed[c][d]^2 ----------------
__global__ __launch_bounds__(256) void prep_e2(const float* __restrict__ embed,
                                               float* __restrict__ e2) {
  int wave = threadIdx.x >> 6, lane = threadIdx.x & 63;
  int c = blockIdx.x * 4 + wave;
  const float* row = embed + (size_t)c * ND;
  float s = 0.f;
  for (int k = lane; k < ND; k += 64) { float v = row[k]; s = fmaf(v, v, s); }
  for (int off = 32; off > 0; off >>= 1) s += __shfl_down(s, off, 64);
  if (lane == 0) e2[c] = s;
}

// ---------------- init keys + counters ----------------
__global__ __launch_bounds__(256) void vq_init(unsigned long long* __restrict__ pKey,
                                               int* __restrict__ cnt) {
  int i = blockIdx.x * 256 + threadIdx.x;
  pKey[i] = ~0ULL;
  if (i < NCT) cnt[i] = 0;
}

// ---------------- pass 1: bf16 1-product GEMM -> per-(token, code-tile) min ----------------
// m97-shape: 128x128 tile, BK=32, 2 staged streams via DMA, 16 MFMA/wave/kt.
// XOR-swizzled LDS (granule (r,cl) holds source granule cl^((r>>1)&3)):
// conflict-free ds_read_b128, DMA-compatible lane-ordered writes.
__global__ __launch_bounds__(256) void vq_approx(
    const short* __restrict__ xb, const int* __restrict__ len,
    const short* __restrict__ eb, const float* __restrict__ e2g,
    float* __restrict__ tMin) {
  __shared__ short sXb[128 * 32];   // 8 KiB
  __shared__ short sEb[128 * 32];   // 8 KiB

  // 8x64 super-tiles: 512 consecutive blocks share 8 X-tiles (L2) + full eb
  const int gid = blockIdx.x;
  const int tt = (gid >> 9) * 8 + (gid & 7);
  const int ct = (gid & 511) >> 3;
  const int b = tt >> 4, s0 = (tt & 15) * 128;
  if (s0 >= len[b]) return;
  const int row0 = tt * 128, code0 = ct * 128;

  const int tid = threadIdx.x, wave = tid >> 6, lane = tid & 63;
  const int quad = lane >> 4, lid = lane & 15;
  const int wr = wave >> 1, wc = wave & 1;

  const int r0 = tid >> 2;
  const int csrc = (tid & 3) ^ ((tid >> 3) & 3);
  const int ldsg0 = (wave * 64) * 8;
  const int ldsg1 = (256 + wave * 64) * 8;

  const int cswz = quad ^ ((lid >> 1) & 3);
  int aoff[4], boff[4];
#pragma unroll
  for (int i = 0; i < 4; ++i) aoff[i] = (wr * 64 + i * 16 + lid) * 32 + cswz * 8;
#pragma unroll
  for (int j = 0; j < 4; ++j) boff[j] = (wc * 64 + j * 16 + lid) * 32 + cswz * 8;

  const short* pxb = xb + (size_t)(row0 + r0) * ND + csrc * 8;
  const short* peb = eb + (size_t)(code0 + r0) * ND + csrc * 8;

  floatx4 acc[4][4];
#pragma unroll
  for (int i = 0; i < 4; ++i)
#pragma unroll
    for (int j = 0; j < 4; ++j) acc[i][j] = (floatx4){0.f, 0.f, 0.f, 0.f};

  int koff = 0;
  for (int kt = 0; kt < KSTEPS; ++kt, koff += 32) {
    __syncthreads();
    cp16((lp_t)&sXb[ldsg0], (gp_t)(pxb + koff));
    cp16((lp_t)&sXb[ldsg1], (gp_t)(pxb + 64 * ND + koff));
    cp16((lp_t)&sEb[ldsg0], (gp_t)(peb + koff));
    cp16((lp_t)&sEb[ldsg1], (gp_t)(peb + 64 * ND + koff));
    __syncthreads();
    bf16x8 bv[4];
#pragma unroll
    for (int j = 0; j < 4; ++j) bv[j] = *(const bf16x8*)&sEb[boff[j]];
#pragma unroll
    for (int i = 0; i < 4; ++i) {
      bf16x8 av = *(const bf16x8*)&sXb[aoff[i]];
#pragma unroll
      for (int j = 0; j < 4; ++j)
        acc[i][j] = __builtin_amdgcn_mfma_f32_16x16x32_bf16(av, bv[j], acc[i][j], 0, 0, 0);
    }
  }

  // per-token min over this 128-code tile (value only)
  float e2v[4];
#pragma unroll
  for (int j = 0; j < 4; ++j) e2v[j] = e2g[code0 + wc * 64 + j * 16 + lid];

  __syncthreads();                  // all waves done with LDS -> alias scratch
  float* sc = (float*)sXb;          // [128][2]
#pragma unroll
  for (int i = 0; i < 4; ++i) {
#pragma unroll
    for (int reg = 0; reg < 4; ++reg) {
      float best = fmaf(-2.0f, acc[i][0][reg], e2v[0]);
#pragma unroll
      for (int j = 1; j < 4; ++j)
        best = fminf(best, fmaf(-2.0f, acc[i][j][reg], e2v[j]));
#pragma unroll
      for (int m = 1; m < 16; m <<= 1) best = fminf(best, __shfl_xor(best, m, 64));
      if (lid == 0) sc[(wr * 64 + i * 16 + quad * 4 + reg) * 2 + wc] = best;
    }
  }
  __syncthreads();
  if (tid < 128)
    tMin[(size_t)(row0 + tid) * NCT + ct] = fminf(sc[tid * 2], sc[tid * 2 + 1]);
}

// ---------------- pass 2: select candidate tiles per token ----------------
__global__ __launch_bounds__(256) void vq_select(
    const int* __restrict__ len, const float* __restrict__ tMin,
    int* __restrict__ list, int* __restrict__ cnt) {
  int wave = threadIdx.x >> 6, lane = threadIdx.x & 63;
  int t = blockIdx.x * 4 + wave;
  int b = t >> 11, s = t & (NSEQ - 1);
  if (s >= len[b]) return;   // wave-uniform
  float v = tMin[(size_t)t * NCT + lane];
  float m = v;
#pragma unroll
  for (int d = 1; d < 64; d <<= 1) m = fminf(m, __shfl_xor(m, d, 64));
  if (v <= m + MARGIN) {
    int pos = atomicAdd(&cnt[lane], 1);
    list[lane * NTOK + pos] = t;
  }
}

// ---------------- pass 3: exact 3-product f16 rescore of selected tiles ----------------
// Block: code tile j, 128 gathered tokens per segment; R3-identical arithmetic
// (same kt order, same hh/hl/lh MFMA order, same fold) -> bit-identical scores
// to the R3 run; argmin combined via atomicMin on sortable (score,idx) key.
__global__ __launch_bounds__(256) void vq_rescore(
    const float* __restrict__ x,
    const _Float16* __restrict__ eh, const _Float16* __restrict__ el,
    const float* __restrict__ e2g,
    const int* __restrict__ list, const int* __restrict__ cnt,
    unsigned long long* __restrict__ pKey) {
  __shared__ _Float16 sXh[128 * 32];
  __shared__ _Float16 sXl[128 * 32];
  __shared__ _Float16 sEh[128 * 32];
  __shared__ _Float16 sEl[128 * 32];

  const int j = blockIdx.x;
  const int n = cnt[j];
  const int code0 = j * 128;

  const int tid = threadIdx.x, wave = tid >> 6, lane = tid & 63;
  const int quad = lane >> 4, lid = lane & 15;
  const int wr = wave >> 1, wc = wave & 1;

  const int r0 = tid >> 2;
  const int csrc = (tid & 3) ^ ((tid >> 3) & 3);
  const int ldsg0 = (wave * 64) * 8;
  const int ldsg1 = (256 + wave * 64) * 8;

  const int cswz = quad ^ ((lid >> 1) & 3);
  int aoff[4], boff[4];
#pragma unroll
  for (int i = 0; i < 4; ++i) aoff[i] = (wr * 64 + i * 16 + lid) * 32 + cswz * 8;
#pragma unroll
  for (int jj = 0; jj < 4; ++jj) boff[jj] = (wc * 64 + jj * 16 + lid) * 32 + cswz * 8;

  const _Float16* peh = eh + (size_t)(code0 + r0) * ND + csrc * 8;
  const _Float16* pel = el + (size_t)(code0 + r0) * ND + csrc * 8;

  float e2v[4]; int cjv[4];
#pragma unroll
  for (int jj = 0; jj < 4; ++jj) {
    cjv[jj] = code0 + wc * 64 + jj * 16 + lid;   // C/D layout: col = lane&15
    e2v[jj] = e2g[cjv[jj]];
  }

  for (int seg = blockIdx.y; seg * 128 < n; seg += gridDim.y) {
    const int base = seg * 128;
    const int tok0 = list[j * NTOK + min(base + r0, n - 1)];        // clamp: dup of
    const int tok1 = list[j * NTOK + min(base + 64 + r0, n - 1)];   // last is idempotent
    const float* px0 = x + (size_t)tok0 * ND + csrc * 8;
    const float* px1 = x + (size_t)tok1 * ND + csrc * 8;

    floatx4 acc[4][4];
#pragma unroll
    for (int i = 0; i < 4; ++i)
#pragma unroll
      for (int jj = 0; jj < 4; ++jj) acc[i][jj] = (floatx4){0.f, 0.f, 0.f, 0.f};

    int koff = 0;
    for (int kt = 0; kt < KSTEPS; ++kt, koff += 32) {
      __syncthreads();
      // X: gathered rows, fp32 -> scaled f16 split (same convert as R3's prep_x)
      const float* srcs[2] = {px0 + koff, px1 + koff};
#pragma unroll
      for (int it = 0; it < 2; ++it) {
        float4 a = *(const float4*)srcs[it];
        float4 c = *(const float4*)(srcs[it] + 4);
        float vs[8] = {a.x, a.y, a.z, a.w, c.x, c.y, c.z, c.w};
        half8 h, l;
#pragma unroll
        for (int q = 0; q < 8; ++q) {
          float vv = XSCALE * vs[q];
          _Float16 hh = (_Float16)vv;
          h[q] = hh;
          l[q] = (_Float16)(vv - (float)hh);
        }
        *(half8*)&sXh[(it * 256 + tid) * 8] = h;
        *(half8*)&sXl[(it * 256 + tid) * 8] = l;
      }
      cp16((lp_t)&sEh[ldsg0], (gp_t)(peh + koff));
      cp16((lp_t)&sEh[ldsg1], (gp_t)(peh + 64 * ND + koff));
      cp16((lp_t)&sEl[ldsg0], (gp_t)(pel + koff));
      cp16((lp_t)&sEl[ldsg1], (gp_t)(pel + 64 * ND + koff));
      __syncthreads();

      half8 bh[4], bl[4];
#pragma unroll
      for (int jj = 0; jj < 4; ++jj) {
        bh[jj] = *(const half8*)&sEh[boff[jj]];
        bl[jj] = *(const half8*)&sEl[boff[jj]];
      }
#pragma unroll
      for (int i = 0; i < 4; ++i) {
        half8 ah = *(const half8*)&sXh[aoff[i]];
        half8 al = *(const half8*)&sXl[aoff[i]];
#pragma unroll
        for (int jj = 0; jj < 4; ++jj) {
          acc[i][jj] = __builtin_amdgcn_mfma_f32_16x16x32_f16(ah, bh[jj], acc[i][jj], 0, 0, 0);
          acc[i][jj] = __builtin_amdgcn_mfma_f32_16x16x32_f16(ah, bl[jj], acc[i][jj], 0, 0, 0);
          acc[i][jj] = __builtin_amdgcn_mfma_f32_16x16x32_f16(al, bh[jj], acc[i][jj], 0, 0, 0);
        }
      }
    }

    // epilogue: per-row argmin over the 128 codes, publish via atomicMin
#pragma unroll
    for (int i = 0; i < 4; ++i) {
#pragma unroll
      for (int reg = 0; reg < 4; ++reg) {
        float best = fmaf(-SCORE_SCALE, acc[i][0][reg], e2v[0]);
        int bidx = cjv[0];
#pragma unroll
        for (int jj = 1; jj < 4; ++jj) {
          float vj = fmaf(-SCORE_SCALE, acc[i][jj][reg], e2v[jj]);
          if (vj < best) { best = vj; bidx = cjv[jj]; }   // strict <: lowest idx on ties
        }
#pragma unroll
        for (int m = 1; m < 16; m <<= 1) {
          float ov = __shfl_xor(best, m, 64);
          int   oi = __shfl_xor(bidx, m, 64);
          if (ov < best || (ov == best && oi < bidx)) { best = ov; bidx = oi; }
        }
        if (lid == 0) {
          int row = wr * 64 + i * 16 + quad * 4 + reg;    // C/D row = quad*4+reg
          int t = list[j * NTOK + min(base + row, n - 1)];
          if (best == 0.0f) best = 0.0f;                  // normalize -0
          unsigned u = __float_as_uint(best);
          u ^= (u >> 31) ? 0xFFFFFFFFu : 0x80000000u;     // sortable fp32
          unsigned long long key = ((unsigned long long)u << 32) | (unsigned)bidx;
          atomicMin(&pKey[t], key);
        }
      }
    }
  }
}

// ---------------- decode key, gather code row, apply mask ----------------
__global__ __launch_bounds__(256) void vq_output(
    const float* __restrict__ embed, const int* __restrict__ len,
    const unsigned long long* __restrict__ pKey,
    float* __restrict__ out) {
  int wave = threadIdx.x >> 6, lane = threadIdx.x & 63;
  int t = blockIdx.x * 4 + wave;
  int b = t >> 11, s = t & (NSEQ - 1);
  float* outq = out + (size_t)t * ND;
  float* outind = out + (size_t)NTOK * ND;
  if (s >= len[b]) {
    float4 z = {0.f, 0.f, 0.f, 0.f};
    *(float4*)&outq[lane * 8]     = z;
    *(float4*)&outq[lane * 8 + 4] = z;
    if (lane == 0) outind[t] = -1.0f;
    return;
  }
  unsigned long long key = pKey[t];
  int bi = (int)(unsigned)(key & 0xFFFFFFFFULL);
  const float* er = embed + (size_t)bi * ND;
  *(float4*)&outq[lane * 8]     = *(const float4*)&er[lane * 8];
  *(float4*)&outq[lane * 8 + 4] = *(const float4*)&er[lane * 8 + 4];
  if (lane == 0) outind[t] = (float)bi;
}

extern "C" void kernel_launch(void* const* d_in, const int* in_sizes, int n_in,
                              void* d_out, int out_size, void* d_ws, size_t ws_size,
                              hipStream_t stream) {
  const float* x     = (const float*)d_in[0];
  const int*   lenp  = (const int*)d_in[1];
  const float* embed = (const float*)d_in[2];
  float* out = (float*)d_out;

  // ws: eb 8M | eh 8M | el 8M | e2 32K | xb 32M | tMin 8M | list 8M | cnt | pKey  ~72.5 MB
  char* w = (char*)d_ws;
  size_t off = 0;
  short*    eb = (short*)(w + off);    off += (size_t)NC * ND * 2;
  _Float16* eh = (_Float16*)(w + off); off += (size_t)NC * ND * 2;
  _Float16* el = (_Float16*)(w + off); off += (size_t)NC * ND * 2;
  float*    e2 = (float*)(w + off);    off += (size_t)NC * 4;
  short*    xb = (short*)(w + off);    off += (size_t)NTOK * ND * 2;
  float*  tMin = (float*)(w + off);    off += (size_t)NTOK * NCT * 4;
  int*    list = (int*)(w + off);      off += (size_t)NCT * NTOK * 4;
  int*     cnt = (int*)(w + off);      off += 256;
  unsigned long long* pKey = (unsigned long long*)(w + off); off += (size_t)NTOK * 8;

  prep_embed<<<1024, 256, 0, stream>>>(embed, eb, eh, el);
  prep_e2<<<NC / 4, 256, 0, stream>>>(embed, e2);
  prep_xb<<<2048, 256, 0, stream>>>(x, xb);
  vq_init<<<NTOK / 256, 256, 0, stream>>>(pKey, cnt);
  vq_approx<<<NTT * NCT, 256, 0, stream>>>(xb, lenp, eb, e2, tMin);
  vq_select<<<NTOK / 4, 256, 0, stream>>>(lenp, tMin, list, cnt);
  vq_rescore<<<dim3(NCT, 8), 256, 0, stream>>>(x, eh, el, e2, list, cnt, pKey);
  vq_output<<<NTOK / 4, 256, 0, stream>>>(embed, lenp, pKey, out);
}